// Round 9
// baseline (1097.043 us; speedup 1.0000x reference)
//
#include <hip/hip_runtime.h>
#include <hip/hip_fp16.h>
#include <math.h>

#define SCAN_BLOCK 1024
#define BK_BITS 8
#define BKSZ 256                 // nodes per bucket (one block per bucket)
#define CH 32768                 // HO edges per chunk (pass A/C must match)
#define FXS 33554432.0f          // 2^25 fixed-point scale for per-bucket deg sums

static __device__ __forceinline__ float elu_f(float x) {
    return x > 0.0f ? x : expm1f(x);
}

// ---------------- pass A ----------------
// blocks [0, nChunks): per-chunk LDS bucket histogram of HO dst (no global atomics)
// blocks [nChunks, nChunks+biB): BI rank atomics
// blocks [nChunks+biB, ...): A = x @ W220 (fp16 out), 64-row LDS tiles

__global__ __launch_bounds__(256) void k_passA(
    const int* __restrict__ hd, int* __restrict__ counts, int nChunks, int Eho, int NB,
    const int* __restrict__ bd, int* __restrict__ cntBI, unsigned short* __restrict__ rankBI,
    int Ebi, int biB,
    const float* __restrict__ x, const float* __restrict__ W, __half* __restrict__ Axw, int N)
{
    __shared__ float smem[64 * 61 + 960];     // union: bucket hist / xw staging
    int bid = blockIdx.x;
    if (bid < nChunks) {
        unsigned* h = (unsigned*)smem;
        for (int t = threadIdx.x; t < NB; t += 256) h[t] = 0u;
        __syncthreads();
        int e0 = bid * CH;
        int e1 = e0 + CH; if (e1 > Eho) e1 = Eho;
        for (int e = e0 + threadIdx.x; e < e1; e += 256)
            atomicAdd(&h[(unsigned)hd[e] >> BK_BITS], 1u);
        __syncthreads();
        for (int t = threadIdx.x; t < NB; t += 256)
            counts[(size_t)t * nChunks + bid] = (int)h[t];
        return;
    }
    bid -= nChunks;
    if (bid < biB) {
        int i = bid * 256 + threadIdx.x;
        int stride = biB * 256;
        for (; i < Ebi; i += stride)
            rankBI[i] = (unsigned short)atomicAdd(&cntBI[bd[i]], 1);
        return;
    }
    bid -= biB;
    float* sx = smem;
    float* sW = smem + 64 * 61;
    for (int t = threadIdx.x; t < 960; t += 256) sW[t] = W[t];
    int base = bid * 64;
    int rows = N - base; if (rows > 64) rows = 64;
    const float4* xg = (const float4*)(x + (size_t)base * 60);
    int nf4 = rows * 15;
    for (int j = threadIdx.x; j < nf4; j += 256) {
        float4 v = xg[j];
        int r = j / 15, k4 = j - r * 15;
        float* dst = &sx[r * 61 + k4 * 4];
        dst[0] = v.x; dst[1] = v.y; dst[2] = v.z; dst[3] = v.w;
    }
    __syncthreads();
    int t = threadIdx.x;
    if (t < rows) {
        const float* xr = &sx[t * 61];
        float acc[16];
        #pragma unroll
        for (int o = 0; o < 16; o++) acc[o] = 0.0f;
        #pragma unroll
        for (int k = 0; k < 60; k++) {
            float xv = xr[k];
            #pragma unroll
            for (int o = 0; o < 16; o++) acc[o] = fmaf(xv, sW[k * 16 + o], acc[o]);
        }
        __half2 hh[8];
        #pragma unroll
        for (int j = 0; j < 8; j++) hh[j] = __floats2half2_rn(acc[2 * j], acc[2 * j + 1]);
        uint4* yr = (uint4*)(Axw + (size_t)(base + t) * 16);
        yr[0] = *(uint4*)&hh[0];
        yr[1] = *(uint4*)&hh[4];
    }
}

// ---------------- fused two-range exclusive scan ----------------

__global__ void k_scan2(const int* __restrict__ in1, int* __restrict__ out1, int n1, int nb1,
                        const int* __restrict__ in2, int* __restrict__ out2, int n2,
                        int* __restrict__ sums1, int* __restrict__ sums2) {
    __shared__ int tmp[SCAN_BLOCK];
    int b = blockIdx.x;
    const int* in; int* out; int n; int* sums; int bb;
    if (b < nb1) { in = in1; out = out1; n = n1; sums = sums1; bb = b; }
    else         { in = in2; out = out2; n = n2; sums = sums2; bb = b - nb1; }
    int gid = bb * SCAN_BLOCK + threadIdx.x;
    int v = (gid < n) ? in[gid] : 0;
    tmp[threadIdx.x] = v;
    __syncthreads();
    for (int off = 1; off < SCAN_BLOCK; off <<= 1) {
        int t = (threadIdx.x >= off) ? tmp[threadIdx.x - off] : 0;
        __syncthreads();
        tmp[threadIdx.x] += t;
        __syncthreads();
    }
    if (gid < n) out[gid] = tmp[threadIdx.x] - v;
    if (threadIdx.x == SCAN_BLOCK - 1) sums[bb] = tmp[threadIdx.x];
}

__global__ void k_scan_sums2(int* __restrict__ sums1, int nb1,
                             int* __restrict__ sums2, int nb2) {
    __shared__ int tmp[SCAN_BLOCK];
    int* s = (blockIdx.x == 0) ? sums1 : sums2;
    int nb = (blockIdx.x == 0) ? nb1 : nb2;
    int v = (threadIdx.x < nb) ? s[threadIdx.x] : 0;
    tmp[threadIdx.x] = v;
    __syncthreads();
    for (int off = 1; off < SCAN_BLOCK; off <<= 1) {
        int t = (threadIdx.x >= off) ? tmp[threadIdx.x - off] : 0;
        __syncthreads();
        tmp[threadIdx.x] += t;
        __syncthreads();
    }
    if (threadIdx.x < nb) s[threadIdx.x] = tmp[threadIdx.x] - v;
}

__global__ void k_scan_add2(int* __restrict__ out1, const int* __restrict__ sums1,
                            int n1, int tot1, int nb1,
                            int* __restrict__ out2, const int* __restrict__ sums2,
                            int n2, int tot2) {
    int b = blockIdx.x;
    if (b < nb1) {
        int gid = b * SCAN_BLOCK + threadIdx.x;
        if (gid < n1) out1[gid] += sums1[b];
        if (gid == 0) out1[n1] = tot1;
    } else {
        int b2 = b - nb1;
        int gid = b2 * SCAN_BLOCK + threadIdx.x;
        if (gid < n2) out2[gid] += sums2[b2];
        if (gid == 0) out2[n2] = tot2;
    }
}

// ---------------- pass C: bucket-ordered scatter (LDS cursors) + BI fill ----------------
// eS[pos] = (src | nodeLow<<19, w) -- src < 2^19, nodeLow 8 bits.

__global__ __launch_bounds__(256) void k_passC(
    const int* __restrict__ hs, const int* __restrict__ hd, const float* __restrict__ hw,
    const int* __restrict__ countsS, int nChunks, int NB, int Eho,
    int2* __restrict__ eS,
    const int* __restrict__ bs, const int* __restrict__ bd,
    const unsigned short* __restrict__ rankBI, const int* __restrict__ rsbi,
    int* __restrict__ srcbi, int Ebi)
{
    __shared__ int cur[1600];
    int bid = blockIdx.x;
    if (bid < nChunks) {
        for (int t = threadIdx.x; t < NB; t += 256)
            cur[t] = countsS[(size_t)t * nChunks + bid];
        __syncthreads();
        int e0 = bid * CH;
        int e1 = e0 + CH; if (e1 > Eho) e1 = Eho;
        for (int e = e0 + threadIdx.x; e < e1; e += 256) {
            int d = hd[e];
            int pos = atomicAdd(&cur[(unsigned)d >> BK_BITS], 1);
            eS[pos] = make_int2(hs[e] | ((d & (BKSZ - 1)) << 19), __float_as_int(hw[e]));
        }
        return;
    }
    bid -= nChunks;
    int i = bid * 256 + threadIdx.x;
    int stride = ((int)gridDim.x - nChunks) * 256;
    for (; i < Ebi; i += stride)
        srcbi[rsbi[bd[i]] + rankBI[i]] = bs[i];
}

// ---------------- pass D': per-bucket dinv + A' = dinv * A (fp16) ----------------

__global__ __launch_bounds__(256) void k_passD2(
    const int2* __restrict__ eS, const int* __restrict__ countsS, int nChunks,
    int NHO, float* __restrict__ dinv, __half* __restrict__ Ah)
{
    __shared__ unsigned fx[BKSZ];
    __shared__ float sdinv[BKSZ];
    int b = blockIdx.x;
    int base = countsS[(size_t)b * nChunks];
    int end  = countsS[(size_t)(b + 1) * nChunks];
    int tid = threadIdx.x;
    fx[tid] = 0u;
    __syncthreads();
    for (int e = base + tid; e < end; e += 256) {
        int2 p = eS[e];
        atomicAdd(&fx[(unsigned)p.x >> 19], (unsigned)(__int_as_float(p.y) * FXS + 0.5f));
    }
    __syncthreads();
    int gbase = b * BKSZ;
    int nn = NHO - gbase; if (nn > BKSZ) nn = BKSZ;
    int gn = gbase + tid;
    if (tid < nn) {
        float di = rsqrtf((float)fx[tid] * (1.0f / FXS) + 1.0f);
        dinv[gn] = di;
        sdinv[tid] = di;
    }
    __syncthreads();
    for (int idx = tid; idx < nn * 16; idx += 256) {
        int n = idx >> 4;
        size_t a = (size_t)(gbase + n) * 16 + (idx & 15);
        Ah[a] = __float2half_rn(__half2float(Ah[a]) * sdinv[n]);
    }
}

// edge-accumulate macro: 16 edges loaded coalesced per 16-lane group,
// broadcast via shfl, fp16 row gather, LDS fp32 atomic accumulate per (node,feat)
#define EDGE_ACC(TAB, J) { \
    int px_ = __shfl(p.x, (J), 16); \
    float w_ = __int_as_float(__shfl(p.y, (J), 16)); \
    float v_ = __half2float(TAB[(size_t)(px_ & 0x7FFFF) * 16 + ln]); \
    atomicAdd(&acc[(((unsigned)px_ >> 19) << 4) + ln], w_ * v_); }

#define EDGE_PHASE(TAB) \
    for (int k0 = base + g * 16; k0 < end; k0 += 256) { \
        int take = end - k0; if (take > 16) take = 16; \
        int2 p = eS[k0 + (ln < take ? ln : take - 1)]; \
        if (take == 16) { \
            _Pragma("unroll") \
            for (int j = 0; j < 16; j++) { EDGE_ACC(TAB, j) } \
        } else { \
            int j = 0; \
            if (take >= 8) { \
                _Pragma("unroll") \
                for (int jj = 0; jj < 8; jj++) { EDGE_ACC(TAB, jj) } \
                j = 8; \
            } \
            if (take - j >= 4) { \
                _Pragma("unroll") \
                for (int jj = 0; jj < 4; jj++) { EDGE_ACC(TAB, j + jj) } \
                j += 4; \
            } \
            for (; j < take; j++) { EDGE_ACC(TAB, j) } \
        } \
    }

// ---------------- layer-1 bucket gather: B' = dinv * elu(di*(sum + A'[node]) + b) ----------------

__global__ __launch_bounds__(256) void k_g1b(
    const int2* __restrict__ eS, const int* __restrict__ countsS, int nChunks,
    const float* __restrict__ dinv, const __half* __restrict__ A,
    const float* __restrict__ bias, __half* __restrict__ B, int NHO)
{
    __shared__ float acc[BKSZ * 16];     // 16 KB
    int b = blockIdx.x;
    int base = countsS[(size_t)b * nChunks];
    int end  = countsS[(size_t)(b + 1) * nChunks];
    int tid = threadIdx.x;
    int g = tid >> 4, ln = tid & 15;
    for (int i = tid; i < BKSZ * 16; i += 256) acc[i] = 0.0f;
    __syncthreads();
    EDGE_PHASE(A)
    __syncthreads();
    int gbase = b * BKSZ;
    int nn = NHO - gbase; if (nn > BKSZ) nn = BKSZ;
    for (int idx = tid; idx < nn * 16; idx += 256) {
        int n = idx >> 4, f = idx & 15;
        int gn = gbase + n;
        float di = dinv[gn];
        float v = fmaf(di, acc[idx] + __half2float(A[(size_t)gn * 16 + f]), bias[f]);
        B[(size_t)gn * 16 + f] = __float2half_rn(di * elu_f(v));
    }
}

// ---------------- layer-2 bucket gather fused with W221 + lin1 ----------------

__global__ __launch_bounds__(256) void k_g2b(
    const int2* __restrict__ eS, const int* __restrict__ countsS, int nChunks,
    const float* __restrict__ dinv, const __half* __restrict__ B,
    const float* __restrict__ W221, const float* __restrict__ b221,
    const float* __restrict__ L1w, const float* __restrict__ L1b,
    __half* __restrict__ M, int NHO)
{
    __shared__ float acc[BKSZ * 16];     // 16 KB
    __shared__ float sW[16 * 32];
    __shared__ float sb2[32];
    __shared__ float sL[32 * 32];
    __shared__ float sLb[32];
    int tid = threadIdx.x;
    for (int t = tid; t < 512; t += 256) sW[t] = W221[t];
    for (int t = tid; t < 1024; t += 256) sL[t] = L1w[t];
    if (tid < 32) { sb2[tid] = b221[tid]; sLb[tid] = L1b[tid]; }
    for (int i = tid; i < BKSZ * 16; i += 256) acc[i] = 0.0f;
    int b = blockIdx.x;
    int base = countsS[(size_t)b * nChunks];
    int end  = countsS[(size_t)(b + 1) * nChunks];
    int g = tid >> 4, ln = tid & 15;
    __syncthreads();
    EDGE_PHASE(B)
    __syncthreads();
    int gbase = b * BKSZ;
    int nn = NHO - gbase; if (nn > BKSZ) nn = BKSZ;
    for (int n = g; n < nn; n += 16) {
        int gn = gbase + n;
        float di = dinv[gn];
        float agg = di * (acc[n * 16 + ln] + __half2float(B[(size_t)gn * 16 + ln]));
        float h2a = sb2[ln], h2b = sb2[ln + 16];
        #pragma unroll
        for (int k = 0; k < 16; k++) {
            float ak = __shfl(agg, k, 16);
            h2a += ak * sW[k * 32 + ln];
            h2b += ak * sW[k * 32 + ln + 16];
        }
        h2a = elu_f(h2a); h2b = elu_f(h2b);
        float m0 = sLb[ln], m1 = sLb[ln + 16];
        #pragma unroll
        for (int k = 0; k < 16; k++) {
            float a0 = __shfl(h2a, k, 16);
            float a1 = __shfl(h2b, k, 16);
            m0 += a0 * sL[k * 32 + ln]        + a1 * sL[(k + 16) * 32 + ln];
            m1 += a0 * sL[k * 32 + ln + 16]   + a1 * sL[(k + 16) * 32 + ln + 16];
        }
        __half* mr = M + (size_t)gn * 32;
        mr[ln] = __float2half_rn(m0); mr[ln + 16] = __float2half_rn(m1);
    }
}

// ---------------- bipartite gather fused with MLP head ----------------

__global__ void k_bi_mlp(const int* __restrict__ srcs, const int* __restrict__ rs,
                         const __half* __restrict__ M, const float* __restrict__ mw,
                         const float* __restrict__ mb, float* __restrict__ out, int N) {
    __shared__ float sW[32 * 10];
    __shared__ float sb[10];
    for (int t = threadIdx.x; t < 320; t += blockDim.x) sW[t] = mw[t];
    if (threadIdx.x < 10) sb[threadIdx.x] = mb[threadIdx.x];
    __syncthreads();
    int t = blockIdx.x * blockDim.x + threadIdx.x;
    int node = t >> 5, ln = t & 31;
    if (node >= N) return;
    int beg = rs[node], end = rs[node + 1];
    float acc = 0.0f;
    for (int k = beg; k < end; k += 32) {
        int take = end - k; if (take > 32) take = 32;
        int ms = srcs[k + (ln < take ? ln : take - 1)];
        if (take == 32) {
            #pragma unroll
            for (int j = 0; j < 32; j++)
                acc += __half2float(M[(size_t)__shfl(ms, j, 32) * 32 + ln]);
        } else {
            int j = 0;
            if (take >= 16) {
                #pragma unroll
                for (int jj = 0; jj < 16; jj++)
                    acc += __half2float(M[(size_t)__shfl(ms, jj, 32) * 32 + ln]);
                j = 16;
            }
            if (take - j >= 8) {
                #pragma unroll
                for (int jj = 0; jj < 8; jj++)
                    acc += __half2float(M[(size_t)__shfl(ms, j + jj, 32) * 32 + ln]);
                j += 8;
            }
            if (take - j >= 4) {
                #pragma unroll
                for (int jj = 0; jj < 4; jj++)
                    acc += __half2float(M[(size_t)__shfl(ms, j + jj, 32) * 32 + ln]);
                j += 4;
            }
            for (; j < take; j++)
                acc += __half2float(M[(size_t)__shfl(ms, j, 32) * 32 + ln]);
        }
    }
    float e = elu_f(acc);
    int lw = ln < 10 ? ln : 0;
    float o = ln < 10 ? sb[ln] : 0.0f;
    #pragma unroll
    for (int k = 0; k < 32; k++) {
        float ak = __shfl(e, k, 32);
        o += ak * sW[k * 10 + lw];
    }
    if (ln < 10) out[(size_t)node * 10 + ln] = o;
}

// ---------------- launch ----------------

extern "C" void kernel_launch(void* const* d_in, const int* in_sizes, int n_in,
                              void* d_out, int out_size, void* d_ws, size_t ws_size,
                              hipStream_t stream) {
    const float* x_ho   = (const float*)d_in[0];
    const int*   ho_src = (const int*)d_in[2];
    const int*   ho_dst = (const int*)d_in[3];
    const float* ho_w   = (const float*)d_in[4];
    const int*   bi_src = (const int*)d_in[8];
    const int*   bi_dst = (const int*)d_in[9];
    const float* W220   = (const float*)d_in[12];
    const float* b220   = (const float*)d_in[13];
    const float* W221   = (const float*)d_in[14];
    const float* b221   = (const float*)d_in[15];
    const float* lin1_w = (const float*)d_in[20];
    const float* lin1_b = (const float*)d_in[21];
    const float* mlp_w  = (const float*)d_in[24];
    const float* mlp_b  = (const float*)d_in[25];

    const int NHO = in_sizes[0] / 60;
    const int EHO = in_sizes[2];
    const int EBI = in_sizes[8];
    const int NFO = out_size / 10;
    float* out = (float*)d_out;

    const int NB = (NHO + BKSZ - 1) / BKSZ;              // 1563
    const int nChunks = (EHO + CH - 1) / CH;             // 123
    const int NC = NB * nChunks;
    const int biB = 2048;
    const int xwB = (NHO + 63) / 64;

    // ---- workspace layout (4-byte words); 8B/16B-aligned entries first ----
    size_t off = 0;
    float* ws = (float*)d_ws;
    int2*   eS = (int2*)(ws + off); off += (size_t)2 * EHO;      // alive through g2b
    __half* A  = (__half*)(ws + off); off += (size_t)16 * NHO;   // A' fp16 (16 used); M overlays (32 half)
    __half* M  = A;
    __half* B  = (__half*)(ws + off); off += (size_t)8 * NHO;    // B' fp16
    float* dinv  = ws + off; off += NHO;
    int*   counts  = (int*)(ws + off); off += NC;
    int*   countsS = (int*)(ws + off); off += NC + 1;
    int*   cntBI = (int*)(ws + off); off += NFO;
    int*   rs_bi = (int*)(ws + off); off += NFO + 1;
    int*   srcbi = (int*)(ws + off); off += EBI;
    unsigned short* rankBI = (unsigned short*)(ws + off); off += (EBI + 1) / 2;
    int*   sums1 = (int*)(ws + off); off += SCAN_BLOCK;
    int*   sums2 = (int*)(ws + off); off += SCAN_BLOCK;

    const int BLK = 256;
    const int nb1 = (NC + SCAN_BLOCK - 1) / SCAN_BLOCK;
    const int nb2 = (NFO + SCAN_BLOCK - 1) / SCAN_BLOCK;

    // zero only the BI atomic counters
    hipMemsetAsync(cntBI, 0, (size_t)NFO * 4, stream);

    // pass A: HO bucket hist (LDS) || BI atomics || x @ W220 (fp16)
    k_passA<<<nChunks + biB + xwB, BLK, 0, stream>>>(
        ho_dst, counts, nChunks, EHO, NB,
        bi_dst, cntBI, rankBI, EBI, biB,
        x_ho, W220, A, NHO);

    // scans: counts matrix (bucket-major) and BI counters
    k_scan2<<<nb1 + nb2, SCAN_BLOCK, 0, stream>>>(
        counts, countsS, NC, nb1, cntBI, rs_bi, NFO, sums1, sums2);
    k_scan_sums2<<<2, SCAN_BLOCK, 0, stream>>>(sums1, nb1, sums2, nb2);
    k_scan_add2<<<nb1 + nb2, SCAN_BLOCK, 0, stream>>>(
        countsS, sums1, NC, EHO, nb1, rs_bi, sums2, NFO, EBI);

    // pass C: bucket-ordered scatter + BI fill
    k_passC<<<nChunks + 2048, BLK, 0, stream>>>(
        ho_src, ho_dst, ho_w, countsS, nChunks, NB, EHO, eS,
        bi_src, bi_dst, rankBI, rs_bi, srcbi, EBI);

    // pass D': per-bucket dinv + A' = dinv*A (no CSR build)
    k_passD2<<<NB, BLK, 0, stream>>>(eS, countsS, nChunks, NHO, dinv, A);

    // B' = dinv * elu(gcn1)   (bucket LDS-accumulate from eS)
    k_g1b<<<NB, BLK, 0, stream>>>(eS, countsS, nChunks, dinv, A, b220, B, NHO);

    // M = (elu(gcn2)) @ lin1 + lin1_b   (bucket LDS-accumulate from eS, fp16)
    k_g2b<<<NB, BLK, 0, stream>>>(eS, countsS, nChunks, dinv, B,
                                  W221, b221, lin1_w, lin1_b, M, NHO);

    // out = elu(bipartite sum of M) @ mlp_w + mlp_b
    {
        long long t = (long long)NFO * 32;
        k_bi_mlp<<<(int)((t + BLK - 1) / BLK), BLK, 0, stream>>>(
            srcbi, rs_bi, M, mlp_w, mlp_b, out, NFO);
    }
}

// Round 10
// 436.377 us; speedup vs baseline: 2.5140x; 2.5140x over previous
//
#include <hip/hip_runtime.h>
#include <hip/hip_fp16.h>
#include <math.h>

#define SCAN_BLOCK 1024
#define BK_BITS 9
#define BKSZ 512                 // nodes per bucket
#define CH 16384                 // HO edges per chunk (pass A/C must match)
#define FXS 33554432.0f          // 2^25 fixed-point scale for per-bucket deg sums

static __device__ __forceinline__ float elu_f(float x) {
    return x > 0.0f ? x : expm1f(x);
}

// ---------------- pass A ----------------
// blocks [0, nChunks): per-chunk LDS bucket histogram of HO dst (no global atomics)
// blocks [nChunks, nChunks+biB): BI rank atomics
// blocks [nChunks+biB, ...): A = x @ W220 (fp16 out), 64-row LDS tiles

__global__ __launch_bounds__(256) void k_passA(
    const int* __restrict__ hd, int* __restrict__ counts, int nChunks, int Eho, int NB,
    const int* __restrict__ bd, int* __restrict__ cntBI, unsigned short* __restrict__ rankBI,
    int Ebi, int biB,
    const float* __restrict__ x, const float* __restrict__ W, __half* __restrict__ Axw, int N)
{
    __shared__ float smem[64 * 61 + 960];     // union: bucket hist / xw staging
    int bid = blockIdx.x;
    if (bid < nChunks) {
        unsigned* h = (unsigned*)smem;
        for (int t = threadIdx.x; t < NB; t += 256) h[t] = 0u;
        __syncthreads();
        int e0 = bid * CH;
        int e1 = e0 + CH; if (e1 > Eho) e1 = Eho;
        for (int e = e0 + threadIdx.x; e < e1; e += 256)
            atomicAdd(&h[(unsigned)hd[e] >> BK_BITS], 1u);
        __syncthreads();
        for (int t = threadIdx.x; t < NB; t += 256)
            counts[(size_t)t * nChunks + bid] = (int)h[t];
        return;
    }
    bid -= nChunks;
    if (bid < biB) {
        int i = bid * 256 + threadIdx.x;
        int stride = biB * 256;
        for (; i < Ebi; i += stride)
            rankBI[i] = (unsigned short)atomicAdd(&cntBI[bd[i]], 1);
        return;
    }
    bid -= biB;
    float* sx = smem;
    float* sW = smem + 64 * 61;
    for (int t = threadIdx.x; t < 960; t += 256) sW[t] = W[t];
    int base = bid * 64;
    int rows = N - base; if (rows > 64) rows = 64;
    const float4* xg = (const float4*)(x + (size_t)base * 60);
    int nf4 = rows * 15;
    for (int j = threadIdx.x; j < nf4; j += 256) {
        float4 v = xg[j];
        int r = j / 15, k4 = j - r * 15;
        float* dst = &sx[r * 61 + k4 * 4];
        dst[0] = v.x; dst[1] = v.y; dst[2] = v.z; dst[3] = v.w;
    }
    __syncthreads();
    int t = threadIdx.x;
    if (t < rows) {
        const float* xr = &sx[t * 61];
        float acc[16];
        #pragma unroll
        for (int o = 0; o < 16; o++) acc[o] = 0.0f;
        #pragma unroll
        for (int k = 0; k < 60; k++) {
            float xv = xr[k];
            #pragma unroll
            for (int o = 0; o < 16; o++) acc[o] = fmaf(xv, sW[k * 16 + o], acc[o]);
        }
        __half2 hh[8];
        #pragma unroll
        for (int j = 0; j < 8; j++) hh[j] = __floats2half2_rn(acc[2 * j], acc[2 * j + 1]);
        uint4* yr = (uint4*)(Axw + (size_t)(base + t) * 16);
        yr[0] = *(uint4*)&hh[0];
        yr[1] = *(uint4*)&hh[4];
    }
}

// ---------------- fused two-range exclusive scan ----------------

__global__ void k_scan2(const int* __restrict__ in1, int* __restrict__ out1, int n1, int nb1,
                        const int* __restrict__ in2, int* __restrict__ out2, int n2,
                        int* __restrict__ sums1, int* __restrict__ sums2) {
    __shared__ int tmp[SCAN_BLOCK];
    int b = blockIdx.x;
    const int* in; int* out; int n; int* sums; int bb;
    if (b < nb1) { in = in1; out = out1; n = n1; sums = sums1; bb = b; }
    else         { in = in2; out = out2; n = n2; sums = sums2; bb = b - nb1; }
    int gid = bb * SCAN_BLOCK + threadIdx.x;
    int v = (gid < n) ? in[gid] : 0;
    tmp[threadIdx.x] = v;
    __syncthreads();
    for (int off = 1; off < SCAN_BLOCK; off <<= 1) {
        int t = (threadIdx.x >= off) ? tmp[threadIdx.x - off] : 0;
        __syncthreads();
        tmp[threadIdx.x] += t;
        __syncthreads();
    }
    if (gid < n) out[gid] = tmp[threadIdx.x] - v;
    if (threadIdx.x == SCAN_BLOCK - 1) sums[bb] = tmp[threadIdx.x];
}

__global__ void k_scan_sums2(int* __restrict__ sums1, int nb1,
                             int* __restrict__ sums2, int nb2) {
    __shared__ int tmp[SCAN_BLOCK];
    int* s = (blockIdx.x == 0) ? sums1 : sums2;
    int nb = (blockIdx.x == 0) ? nb1 : nb2;
    int v = (threadIdx.x < nb) ? s[threadIdx.x] : 0;
    tmp[threadIdx.x] = v;
    __syncthreads();
    for (int off = 1; off < SCAN_BLOCK; off <<= 1) {
        int t = (threadIdx.x >= off) ? tmp[threadIdx.x - off] : 0;
        __syncthreads();
        tmp[threadIdx.x] += t;
        __syncthreads();
    }
    if (threadIdx.x < nb) s[threadIdx.x] = tmp[threadIdx.x] - v;
}

__global__ void k_scan_add2(int* __restrict__ out1, const int* __restrict__ sums1,
                            int n1, int tot1, int nb1,
                            int* __restrict__ out2, const int* __restrict__ sums2,
                            int n2, int tot2) {
    int b = blockIdx.x;
    if (b < nb1) {
        int gid = b * SCAN_BLOCK + threadIdx.x;
        if (gid < n1) out1[gid] += sums1[b];
        if (gid == 0) out1[n1] = tot1;
    } else {
        int b2 = b - nb1;
        int gid = b2 * SCAN_BLOCK + threadIdx.x;
        if (gid < n2) out2[gid] += sums2[b2];
        if (gid == 0) out2[n2] = tot2;
    }
}

// ---------------- pass C: bucket-ordered scatter (LDS cursors) + BI fill ----------------

__global__ __launch_bounds__(256) void k_passC(
    const int* __restrict__ hs, const int* __restrict__ hd, const float* __restrict__ hw,
    const int* __restrict__ countsS, int nChunks, int NB, int Eho,
    int2* __restrict__ eS,
    const int* __restrict__ bs, const int* __restrict__ bd,
    const unsigned short* __restrict__ rankBI, const int* __restrict__ rsbi,
    int* __restrict__ srcbi, int Ebi)
{
    __shared__ int cur[1024];
    int bid = blockIdx.x;
    if (bid < nChunks) {
        for (int t = threadIdx.x; t < NB; t += 256)
            cur[t] = countsS[(size_t)t * nChunks + bid];
        __syncthreads();
        int e0 = bid * CH;
        int e1 = e0 + CH; if (e1 > Eho) e1 = Eho;
        for (int e = e0 + threadIdx.x; e < e1; e += 256) {
            int d = hd[e];
            int pos = atomicAdd(&cur[(unsigned)d >> BK_BITS], 1);
            eS[pos] = make_int2(hs[e] | ((d & (BKSZ - 1)) << 19), __float_as_int(hw[e]));
        }
        return;
    }
    bid -= nChunks;
    int i = bid * 256 + threadIdx.x;
    int stride = ((int)gridDim.x - nChunks) * 256;
    for (; i < Ebi; i += stride)
        srcbi[rsbi[bd[i]] + rankBI[i]] = bs[i];
}

// ---------------- pass D: per-bucket CSR finalize + A' = dinv * A (fp16) ----------------

__global__ __launch_bounds__(1024) void k_passD(
    const int2* __restrict__ eS, const int* __restrict__ countsS, int nChunks,
    int NB, int Eho, int NHO,
    int2* __restrict__ pairs, int* __restrict__ rs_ho, float* __restrict__ dinv,
    __half* __restrict__ Ah)
{
    __shared__ unsigned cnt[BKSZ];
    __shared__ unsigned fx[BKSZ];
    __shared__ int sc[BKSZ];
    __shared__ int cur[BKSZ];
    __shared__ float sdinv[BKSZ];
    int b = blockIdx.x;
    int base = countsS[(size_t)b * nChunks];
    int end  = (b == NB - 1) ? Eho : countsS[(size_t)(b + 1) * nChunks];
    int tid = threadIdx.x;
    if (tid < BKSZ) { cnt[tid] = 0u; fx[tid] = 0u; }
    __syncthreads();
    for (int e = base + tid; e < end; e += 1024) {
        int2 p = eS[e];
        int n = (unsigned)p.x >> 19;
        atomicAdd(&cnt[n], 1u);
        atomicAdd(&fx[n], (unsigned)(__int_as_float(p.y) * FXS + 0.5f));
    }
    __syncthreads();
    if (tid < BKSZ) sc[tid] = (int)cnt[tid];
    __syncthreads();
    for (int off = 1; off < BKSZ; off <<= 1) {
        int t = (tid < BKSZ && tid >= off) ? sc[tid - off] : 0;
        __syncthreads();
        if (tid < BKSZ) sc[tid] += t;
        __syncthreads();
    }
    int gbase = b * BKSZ;
    int nn = NHO - gbase; if (nn > BKSZ) nn = BKSZ;
    if (tid < BKSZ) {
        int gn = gbase + tid;
        if (gn < NHO) {
            int off0 = sc[tid] - (int)cnt[tid];       // exclusive
            cur[tid] = base + off0;
            rs_ho[gn] = base + off0;
            float di = rsqrtf((float)fx[tid] * (1.0f / FXS) + 1.0f);
            dinv[gn] = di;
            sdinv[tid] = di;
        }
    }
    if (b == NB - 1 && tid == 0) rs_ho[NHO] = Eho;
    __syncthreads();
    for (int e = base + tid; e < end; e += 1024) {
        int2 p = eS[e];
        int n = (unsigned)p.x >> 19;
        int pos = atomicAdd(&cur[n], 1);
        pairs[pos] = make_int2(p.x & 0x7FFFF, p.y);
    }
    // scale this bucket's A rows by dinv (A' = dinv * A), fp16 in place
    for (int idx = tid; idx < nn * 16; idx += 1024) {
        int n = idx >> 4;
        size_t a = (size_t)(gbase + n) * 16 + (idx & 15);
        Ah[a] = __float2half_rn(__half2float(Ah[a]) * sdinv[n]);
    }
}

// edge-dot macro: 8 edges loaded coalesced per 8-lane group, broadcast via shfl,
// fp16x2 row gather (each lane owns a feature PAIR -> half the instructions/edge)
#define EDGE_FMA2(TAB2, J) { \
    int px_ = __shfl(p.x, (J), 8); \
    float w_ = __int_as_float(__shfl(p.y, (J), 8)); \
    float2 v_ = __half22float2(TAB2[(size_t)px_ * 8 + ln]); \
    ax = fmaf(w_, v_.x, ax); ay = fmaf(w_, v_.y, ay); }

#define EDGE_LOOP2(TAB2) \
    for (int k = beg; k < end; k += 8) { \
        int take = end - k; if (take > 8) take = 8; \
        int2 p = pairs[k + (ln < take ? ln : take - 1)]; \
        if (take == 8) { \
            _Pragma("unroll") \
            for (int j = 0; j < 8; j++) { EDGE_FMA2(TAB2, j) } \
        } else { \
            int j = 0; \
            if (take >= 4) { \
                _Pragma("unroll") \
                for (int jj = 0; jj < 4; jj++) { EDGE_FMA2(TAB2, jj) } \
                j = 4; \
            } \
            if (take - j >= 2) { \
                EDGE_FMA2(TAB2, j) EDGE_FMA2(TAB2, j + 1) \
                j += 2; \
            } \
            if (j < take) { EDGE_FMA2(TAB2, j) } \
        } \
    }

// ---------------- layer-1 gather: B' = dinv * elu(di*(sum + A'[node]) + b) ----------------
// 8 lanes per node, each lane owns features {2ln, 2ln+1}.

__global__ void k_gather1(const int2* __restrict__ pairs, const int* __restrict__ rs,
                          const float* __restrict__ dinv, const __half2* __restrict__ A2,
                          const float* __restrict__ b, __half2* __restrict__ B2, int N) {
    int t = blockIdx.x * blockDim.x + threadIdx.x;
    int node = t >> 3, ln = t & 7;
    if (node >= N) return;
    int beg = rs[node], end = rs[node + 1];
    float ax = 0.0f, ay = 0.0f;
    EDGE_LOOP2(A2)
    float di = dinv[node];
    float2 sl = __half22float2(A2[(size_t)node * 8 + ln]);
    float vx = fmaf(di, ax + sl.x, b[2 * ln]);
    float vy = fmaf(di, ay + sl.y, b[2 * ln + 1]);
    B2[(size_t)node * 8 + ln] = __floats2half2_rn(di * elu_f(vx), di * elu_f(vy));
}

// ---------------- layer-2 gather fused with W221 + lin1 ----------------
// Phase 1 (8 lanes/node, 32 nodes/block): gather agg into LDS.
// Phase 2 (16 lanes/node): proven W221 + lin1 epilogue, agg read from LDS.

__global__ __launch_bounds__(256) void k_gather2(
    const int2* __restrict__ pairs, const int* __restrict__ rs,
    const float* __restrict__ dinv, const __half2* __restrict__ B2,
    const float* __restrict__ W221, const float* __restrict__ b221,
    const float* __restrict__ L1w, const float* __restrict__ L1b,
    __half* __restrict__ M, int N)
{
    __shared__ float sW[16 * 32];
    __shared__ float sb2[32];
    __shared__ float sL[32 * 32];
    __shared__ float sLb[32];
    __shared__ float sAgg[32][17];           // pad 17: conflict-free phase-1 stores
    int tid = threadIdx.x;
    for (int t = tid; t < 512; t += 256) sW[t] = W221[t];
    for (int t = tid; t < 1024; t += 256) sL[t] = L1w[t];
    if (tid < 32) { sb2[tid] = b221[tid]; sLb[tid] = L1b[tid]; }
    __syncthreads();

    int nodeBase = blockIdx.x * 32;
    // phase 1: gather
    {
        int n8 = tid >> 3, ln = tid & 7;
        int node = nodeBase + n8;
        if (node < N) {
            int beg = rs[node], end = rs[node + 1];
            float ax = 0.0f, ay = 0.0f;
            EDGE_LOOP2(B2)
            float di = dinv[node];
            float2 sl = __half22float2(B2[(size_t)node * 8 + ln]);
            sAgg[n8][2 * ln]     = di * (ax + sl.x);
            sAgg[n8][2 * ln + 1] = di * (ay + sl.y);
        }
    }
    __syncthreads();
    // phase 2: dense epilogue (16 lanes/node, 2 iterations of 16 nodes)
    int n16 = tid >> 4, l16 = tid & 15;
    #pragma unroll
    for (int it = 0; it < 2; ++it) {
        int n = it * 16 + n16;
        int gn = nodeBase + n;
        if (gn < N) {
            float h2a = sb2[l16], h2b = sb2[l16 + 16];
            #pragma unroll
            for (int k = 0; k < 16; k++) {
                float ak = sAgg[n][k];
                h2a += ak * sW[k * 32 + l16];
                h2b += ak * sW[k * 32 + l16 + 16];
            }
            h2a = elu_f(h2a); h2b = elu_f(h2b);
            float m0 = sLb[l16], m1 = sLb[l16 + 16];
            #pragma unroll
            for (int k = 0; k < 16; k++) {
                float a0 = __shfl(h2a, k, 16);
                float a1 = __shfl(h2b, k, 16);
                m0 += a0 * sL[k * 32 + l16]        + a1 * sL[(k + 16) * 32 + l16];
                m1 += a0 * sL[k * 32 + l16 + 16]   + a1 * sL[(k + 16) * 32 + l16 + 16];
            }
            __half* mr = M + (size_t)gn * 32;
            mr[l16] = __float2half_rn(m0); mr[l16 + 16] = __float2half_rn(m1);
        }
    }
}

// ---------------- bipartite gather fused with MLP head ----------------
// 32 lanes/node; srcs loaded 32-wide coalesced + shfl broadcast; fp16 M rows (64B).

__global__ void k_bi_mlp(const int* __restrict__ srcs, const int* __restrict__ rs,
                         const __half* __restrict__ M, const float* __restrict__ mw,
                         const float* __restrict__ mb, float* __restrict__ out, int N) {
    __shared__ float sW[32 * 10];
    __shared__ float sb[10];
    for (int t = threadIdx.x; t < 320; t += blockDim.x) sW[t] = mw[t];
    if (threadIdx.x < 10) sb[threadIdx.x] = mb[threadIdx.x];
    __syncthreads();
    int t = blockIdx.x * blockDim.x + threadIdx.x;
    int node = t >> 5, ln = t & 31;
    if (node >= N) return;
    int beg = rs[node], end = rs[node + 1];
    float acc = 0.0f;
    for (int k = beg; k < end; k += 32) {
        int take = end - k; if (take > 32) take = 32;
        int ms = srcs[k + (ln < take ? ln : take - 1)];
        if (take == 32) {
            #pragma unroll
            for (int j = 0; j < 32; j++)
                acc += __half2float(M[(size_t)__shfl(ms, j, 32) * 32 + ln]);
        } else {
            int j = 0;
            if (take >= 16) {
                #pragma unroll
                for (int jj = 0; jj < 16; jj++)
                    acc += __half2float(M[(size_t)__shfl(ms, jj, 32) * 32 + ln]);
                j = 16;
            }
            if (take - j >= 8) {
                #pragma unroll
                for (int jj = 0; jj < 8; jj++)
                    acc += __half2float(M[(size_t)__shfl(ms, j + jj, 32) * 32 + ln]);
                j += 8;
            }
            if (take - j >= 4) {
                #pragma unroll
                for (int jj = 0; jj < 4; jj++)
                    acc += __half2float(M[(size_t)__shfl(ms, j + jj, 32) * 32 + ln]);
                j += 4;
            }
            for (; j < take; j++)
                acc += __half2float(M[(size_t)__shfl(ms, j, 32) * 32 + ln]);
        }
    }
    float e = elu_f(acc);
    int lw = ln < 10 ? ln : 0;
    float o = ln < 10 ? sb[ln] : 0.0f;
    #pragma unroll
    for (int k = 0; k < 32; k++) {
        float ak = __shfl(e, k, 32);
        o += ak * sW[k * 10 + lw];
    }
    if (ln < 10) out[(size_t)node * 10 + ln] = o;
}

// ---------------- launch ----------------

extern "C" void kernel_launch(void* const* d_in, const int* in_sizes, int n_in,
                              void* d_out, int out_size, void* d_ws, size_t ws_size,
                              hipStream_t stream) {
    const float* x_ho   = (const float*)d_in[0];
    const int*   ho_src = (const int*)d_in[2];
    const int*   ho_dst = (const int*)d_in[3];
    const float* ho_w   = (const float*)d_in[4];
    const int*   bi_src = (const int*)d_in[8];
    const int*   bi_dst = (const int*)d_in[9];
    const float* W220   = (const float*)d_in[12];
    const float* b220   = (const float*)d_in[13];
    const float* W221   = (const float*)d_in[14];
    const float* b221   = (const float*)d_in[15];
    const float* lin1_w = (const float*)d_in[20];
    const float* lin1_b = (const float*)d_in[21];
    const float* mlp_w  = (const float*)d_in[24];
    const float* mlp_b  = (const float*)d_in[25];

    const int NHO = in_sizes[0] / 60;
    const int EHO = in_sizes[2];
    const int EBI = in_sizes[8];
    const int NFO = out_size / 10;
    float* out = (float*)d_out;

    const int NB = (NHO + BKSZ - 1) / BKSZ;              // 782
    const int nChunks = (EHO + CH - 1) / CH;             // 245
    const int NC = NB * nChunks;
    const int biB = 2048;
    const int xwB = (NHO + 63) / 64;

    // ---- workspace layout (4-byte words); 8B/16B-aligned entries first ----
    size_t off = 0;
    float* ws = (float*)d_ws;
    int2*  pairs = (int2*)(ws + off); off += (size_t)2 * EHO;
    size_t uWords = (size_t)2 * EHO;                     // U = max(eS, B' fp16)
    if ((size_t)8 * NHO > uWords) uWords = (size_t)8 * NHO;
    int2*   eS = (int2*)(ws + off);
    __half* B  = (__half*)(ws + off); off += uWords;     // eS dead before B is written
    __half* A  = (__half*)(ws + off); off += (size_t)16 * NHO;  // A' fp16 (16 used); M overlays (32 half)
    __half* M  = A;
    float* dinv  = ws + off; off += NHO;
    int*   counts  = (int*)(ws + off); off += NC;
    int*   countsS = (int*)(ws + off); off += NC + 1;
    int*   cntBI = (int*)(ws + off); off += NFO;
    int*   rs_bi = (int*)(ws + off); off += NFO + 1;
    int*   srcbi = (int*)(ws + off); off += EBI;
    int*   rs_ho = (int*)(ws + off); off += NHO + 1;
    unsigned short* rankBI = (unsigned short*)(ws + off); off += (EBI + 1) / 2;
    int*   sums1 = (int*)(ws + off); off += SCAN_BLOCK;
    int*   sums2 = (int*)(ws + off); off += SCAN_BLOCK;

    const int BLK = 256;
    const int nb1 = (NC + SCAN_BLOCK - 1) / SCAN_BLOCK;
    const int nb2 = (NFO + SCAN_BLOCK - 1) / SCAN_BLOCK;

    // zero only the BI atomic counters
    hipMemsetAsync(cntBI, 0, (size_t)NFO * 4, stream);

    // pass A: HO bucket hist (LDS) || BI atomics || x @ W220 (fp16)
    k_passA<<<nChunks + biB + xwB, BLK, 0, stream>>>(
        ho_dst, counts, nChunks, EHO, NB,
        bi_dst, cntBI, rankBI, EBI, biB,
        x_ho, W220, A, NHO);

    // scans: counts matrix (bucket-major) and BI counters
    k_scan2<<<nb1 + nb2, SCAN_BLOCK, 0, stream>>>(
        counts, countsS, NC, nb1, cntBI, rs_bi, NFO, sums1, sums2);
    k_scan_sums2<<<2, SCAN_BLOCK, 0, stream>>>(sums1, nb1, sums2, nb2);
    k_scan_add2<<<nb1 + nb2, SCAN_BLOCK, 0, stream>>>(
        countsS, sums1, NC, EHO, nb1, rs_bi, sums2, NFO, EBI);

    // pass C: bucket-ordered scatter + BI fill
    k_passC<<<nChunks + 2048, BLK, 0, stream>>>(
        ho_src, ho_dst, ho_w, countsS, nChunks, NB, EHO, eS,
        bi_src, bi_dst, rankBI, rs_bi, srcbi, EBI);

    // pass D: per-bucket CSR finalize (rs_ho, dinv, pairs) + A' = dinv*A
    k_passD<<<NB, SCAN_BLOCK, 0, stream>>>(
        eS, countsS, nChunks, NB, EHO, NHO, pairs, rs_ho, dinv, A);

    // B' = dinv * elu(gcn1)   (8 lanes/node, half2)
    {
        long long t = (long long)NHO * 8;
        k_gather1<<<(int)((t + BLK - 1) / BLK), BLK, 0, stream>>>(
            pairs, rs_ho, dinv, (const __half2*)A, b220, (__half2*)B, NHO);
    }
    // M = (elu(gcn2)) @ lin1 + lin1_b   (half2 gather + LDS-staged epilogue)
    {
        int g = (NHO + 31) / 32;
        k_gather2<<<g, BLK, 0, stream>>>(
            pairs, rs_ho, dinv, (const __half2*)B, W221, b221, lin1_w, lin1_b, M, NHO);
    }
    // out = elu(bipartite sum of M) @ mlp_w + mlp_b
    {
        long long t = (long long)NFO * 32;
        k_bi_mlp<<<(int)((t + BLK - 1) / BLK), BLK, 0, stream>>>(
            srcbi, rs_bi, M, mlp_w, mlp_b, out, NFO);
    }
}